// Round 5
// baseline (18135.643 us; speedup 1.0000x reference)
//
#include <hip/hip_runtime.h>

typedef unsigned short u16;
typedef unsigned int u32;
typedef unsigned long long u64;
typedef __bf16 bf16x8 __attribute__((ext_vector_type(8)));
typedef float f32x4 __attribute__((ext_vector_type(4)));

__device__ __forceinline__ u16 f2b(float f) {
  unsigned u = __float_as_uint(f);
  return (u16)((u + 0x7fffu + ((u >> 16) & 1u)) >> 16);
}
__device__ __forceinline__ float b2f(u16 h) {
  return __uint_as_float(((unsigned)h) << 16);
}

// LLC-coherent (agent-scope relaxed: plain instr with sc bits, no cache-maint fences)
__device__ __forceinline__ void st_b16_llc(u16* p, u16 v) {
  __hip_atomic_store(p, v, __ATOMIC_RELAXED, __HIP_MEMORY_SCOPE_AGENT);
}
__device__ __forceinline__ bf16x8 ld_frag_llc(const u16* p) {
  union { u64 q[2]; bf16x8 v; } u;
  u.q[0] = __hip_atomic_load((const u64*)p,     __ATOMIC_RELAXED, __HIP_MEMORY_SCOPE_AGENT);
  u.q[1] = __hip_atomic_load((const u64*)p + 1, __ATOMIC_RELAXED, __HIP_MEMORY_SCOPE_AGENT);
  return u.v;
}

// ---------------- generic fp32 -> bf16 cast ----------------
__global__ void cast_f32_bf16(const float* __restrict__ in, u16* __restrict__ out, int n) {
  int i = blockIdx.x * 256 + threadIdx.x;
  if (i < n) out[i] = f2b(in[i]);
}

// ---------------- per-wave fence-free barrier ----------------
// 256 wave-slots (128 wgs x 2 waves). Each wave: drain own vmcnt (publishes
// retired to LLC), store own slot, poll all 256 slots (4 per lane).
// asm "memory" clobber pins compiler order: publishes < slot store < polls.
__device__ __forceinline__ void wave_bar(unsigned* __restrict__ slots, unsigned ep,
                                         int ws, int lane) {
  asm volatile("s_waitcnt vmcnt(0)" ::: "memory");
  if (lane == 0)
    __hip_atomic_store(&slots[ws], ep, __ATOMIC_RELAXED, __HIP_MEMORY_SCOPE_AGENT);
  unsigned m;
  do {
    unsigned a = __hip_atomic_load(&slots[lane],        __ATOMIC_RELAXED, __HIP_MEMORY_SCOPE_AGENT);
    unsigned b = __hip_atomic_load(&slots[64 + lane],   __ATOMIC_RELAXED, __HIP_MEMORY_SCOPE_AGENT);
    unsigned c = __hip_atomic_load(&slots[128 + lane],  __ATOMIC_RELAXED, __HIP_MEMORY_SCOPE_AGENT);
    unsigned d = __hip_atomic_load(&slots[192 + lane],  __ATOMIC_RELAXED, __HIP_MEMORY_SCOPE_AGENT);
    m = min(min(a, b), min(c, d));
  } while (m < ep);
}

// ---------------- tiled bf16 GEMM: C[M,N] = A[M,K] @ B[N,K]^T ----------------
// mode 0: Cf[m*N+n] = acc (+bias[n])         (fp32 out)
// mode 1: Cb[(m&511)*32768 + (m>>9)*1024 + n] = bf16(acc)   (gates layout [t][b][n])
__global__ __launch_bounds__(256) void gemm_bt(
    const u16* __restrict__ A, const u16* __restrict__ B,
    int M, int N, int K,
    const float* __restrict__ bias,
    float* __restrict__ Cf, u16* __restrict__ Cb, int mode)
{
  __shared__ u16 a_sm[128 * 32];
  __shared__ u16 b_sm[128 * 32];
  const int tid = threadIdx.x;
  const int lane = tid & 63;
  const int wid = tid >> 6;
  const int wm = wid >> 1, wn = wid & 1;
  const int m0 = blockIdx.x * 128, n0 = blockIdx.y * 128;
  const int q = lane >> 4, l15 = lane & 15, l3 = lane & 3;

  f32x4 acc[4][4];
  #pragma unroll
  for (int i = 0; i < 4; ++i)
    #pragma unroll
    for (int j = 0; j < 4; ++j) acc[i][j] = (f32x4){0.f, 0.f, 0.f, 0.f};

  for (int kk = 0; kk < K; kk += 32) {
    __syncthreads();
    #pragma unroll
    for (int p = 0; p < 2; ++p) {
      int idx = p * 256 + tid;
      int r = idx >> 2, cch = idx & 3;
      *(uint4*)&a_sm[r * 32 + ((cch ^ (r & 3)) * 8)] =
          *(const uint4*)&A[(size_t)(m0 + r) * K + kk + cch * 8];
      *(uint4*)&b_sm[r * 32 + ((cch ^ (r & 3)) * 8)] =
          *(const uint4*)&B[(size_t)(n0 + r) * K + kk + cch * 8];
    }
    __syncthreads();
    bf16x8 af[4], bfr[4];
    #pragma unroll
    for (int s = 0; s < 4; ++s) {
      int ra = wm * 64 + s * 16 + l15;
      af[s] = *(const bf16x8*)&a_sm[ra * 32 + ((q ^ l3) * 8)];
      int rb = wn * 64 + s * 16 + l15;
      bfr[s] = *(const bf16x8*)&b_sm[rb * 32 + ((q ^ l3) * 8)];
    }
    #pragma unroll
    for (int si = 0; si < 4; ++si)
      #pragma unroll
      for (int sj = 0; sj < 4; ++sj)
        acc[si][sj] = __builtin_amdgcn_mfma_f32_16x16x32_bf16(af[si], bfr[sj], acc[si][sj], 0, 0, 0);
  }

  #pragma unroll
  for (int si = 0; si < 4; ++si)
    #pragma unroll
    for (int sj = 0; sj < 4; ++sj)
      #pragma unroll
      for (int e = 0; e < 4; ++e) {
        int m = m0 + wm * 64 + si * 16 + q * 4 + e;
        int n = n0 + wn * 64 + sj * 16 + l15;
        float v = acc[si][sj][e];
        if (mode == 0) {
          if (bias) v += bias[n];
          Cf[(size_t)m * N + n] = v;
        } else {
          Cb[(size_t)(m & 511) * 32768 + (size_t)(m >> 9) * 1024 + n] = f2b(v);
        }
      }
}

// ---------------- persistent GRU layer: 512 steps, 2 per-wave barriers/step ----------------
// 128 wgs x 128 threads (2 waves). wg owns n in [8*bid, 8*bid+8).
// Wave w handles batches w*16 .. w*16+15 over FULL K=1024 (32 MFMAs/phase).
// D-tile lane map (col=n-ish, row=batch) is identical both phases, so the
// recurrence state lives in registers: z-lanes (c15<8) hold h fp32 + z.
// r-lanes (c15>=8) compute r and publish r*h (h via shfl_xor 8).
// Cross-wg h/rh moves only via relaxed agent (LLC) accesses; no fences.
__global__ __launch_bounds__(128, 1) void gru_layer(
    const u16* __restrict__ Wh,                      // [3][1024][1024] bf16 (z,r,g)
    const float* __restrict__ bz, const float* __restrict__ br, const float* __restrict__ bg,
    const u16* __restrict__ gz, const u16* __restrict__ gr, const u16* __restrict__ gg, // [512][32][1024]
    const float* __restrict__ h0,                    // + l*1024, batch stride 2048
    u16* __restrict__ hb, u16* __restrict__ rhb,     // 32x1024 bf16 shared state
    u16* __restrict__ seq,                           // [b][t][n] bf16
    float* __restrict__ hT,                          // + l*1024, batch stride 2048
    unsigned* __restrict__ slots)                    // 256 wave-slots
{
  __shared__ u16 zr_frag[32 * 512];                  // B-frag order, 32 KB
  __shared__ u16 g_frag[32 * 512];                   // 32 KB

  const int tid = threadIdx.x;
  const int lane = tid & 63;
  const int w = tid >> 6;
  const int bid = blockIdx.x;
  const int nb = bid * 8;
  const int q = lane >> 4, c15 = lane & 15;
  const int nl = c15 & 7;
  const int n_own = nb + nl;
  const bool isz = c15 < 8;
  const int ws = bid * 2 + w;

  // ---- stage weights into LDS in exact B-fragment order ----
  for (int cidx = tid; cidx < 2048; cidx += 128) {
    int ks = cidx >> 6;
    int l = cidx & 63;
    int lq = l >> 4, lc = l & 15;
    int gate = (lc < 8) ? 0 : 1;                     // z | r
    const u16* src = Wh + (size_t)gate * 1048576 + (size_t)(nb + (lc & 7)) * 1024 + ks * 32 + lq * 8;
    *(uint4*)&zr_frag[cidx * 8] = *(const uint4*)src;
    const u16* srcg = Wh + (size_t)2 * 1048576 + (size_t)(nb + (lc & 7)) * 1024 + ks * 32 + lq * 8;
    *(uint4*)&g_frag[cidx * 8] = *(const uint4*)srcg;
  }
  __syncthreads();

  int bvec[4];
  #pragma unroll
  for (int e = 0; e < 4; ++e) bvec[e] = w * 16 + q * 4 + e;

  // ---- init h in registers (z-lanes) + publish bf16 h to hb ----
  float hreg[4] = {0.f, 0.f, 0.f, 0.f};
  float zreg[4] = {0.f, 0.f, 0.f, 0.f};
  if (isz) {
    #pragma unroll
    for (int e = 0; e < 4; ++e) {
      hreg[e] = h0[bvec[e] * 2048 + n_own];
      st_b16_llc(&hb[bvec[e] * 1024 + n_own], f2b(hreg[e]));
    }
  }
  const float bias1 = isz ? bz[n_own] : br[n_own];
  const float bias2 = bg[n_own];

  unsigned ep = 1;
  wave_bar(slots, ep, ws, lane);                     // hb init visible everywhere

  // preload z/r gates for t=0 (z-lanes: gz, r-lanes: gr)
  const u16* gbase1 = isz ? gz : gr;
  u16 g1[4];
  #pragma unroll
  for (int e = 0; e < 4; ++e) g1[e] = gbase1[bvec[e] * 1024 + n_own];

  const u16* arow1 = hb + (size_t)(w * 16 + c15) * 1024;
  const u16* arow2 = rhb + (size_t)(w * 16 + c15) * 1024;

  for (int t = 0; t < 512; ++t) {
    // ---------- phase 1: z, r ----------
    {
      f32x4 acc = {0.f, 0.f, 0.f, 0.f};
      #pragma unroll
      for (int ks = 0; ks < 32; ++ks) {
        bf16x8 af = ld_frag_llc(arow1 + ks * 32 + q * 8);
        bf16x8 bf = *(const bf16x8*)&zr_frag[ks * 512 + lane * 8];
        acc = __builtin_amdgcn_mfma_f32_16x16x32_bf16(af, bf, acc, 0, 0, 0);
      }
      // prefetch g-gate for this step (independent of barrier)
      u16 g2[4];
      #pragma unroll
      for (int e = 0; e < 4; ++e) g2[e] = gg[(size_t)t * 32768 + bvec[e] * 1024 + n_own];
      // h of own n for r-lanes (from paired z-lane)
      float hsh[4];
      #pragma unroll
      for (int e = 0; e < 4; ++e) hsh[e] = __shfl_xor(hreg[e], 8);
      #pragma unroll
      for (int e = 0; e < 4; ++e) {
        float pre = acc[e] + bias1 + b2f(g1[e]);
        float s = 1.f / (1.f + __expf(-pre));
        if (isz) zreg[e] = s;
        else     st_b16_llc(&rhb[bvec[e] * 1024 + n_own], f2b(s * hsh[e]));
      }
      wave_bar(slots, ++ep, ws, lane);
      // stash g2 into g1 slot for phase 2 use
      #pragma unroll
      for (int e = 0; e < 4; ++e) g1[e] = g2[e];
    }
    // ---------- phase 2: g, h' ----------
    {
      f32x4 acc = {0.f, 0.f, 0.f, 0.f};
      #pragma unroll
      for (int ks = 0; ks < 32; ++ks) {
        bf16x8 af = ld_frag_llc(arow2 + ks * 32 + q * 8);
        bf16x8 bf = *(const bf16x8*)&g_frag[ks * 512 + lane * 8];
        acc = __builtin_amdgcn_mfma_f32_16x16x32_bf16(af, bf, acc, 0, 0, 0);
      }
      // prefetch z/r gates for t+1
      u16 gnext[4];
      if (t < 511) {
        #pragma unroll
        for (int e = 0; e < 4; ++e) gnext[e] = gbase1[(size_t)(t + 1) * 32768 + bvec[e] * 1024 + n_own];
      }
      if (isz) {
        #pragma unroll
        for (int e = 0; e < 4; ++e) {
          float pre = acc[e] + bias2 + b2f(g1[e]);
          float ex = __expf(2.f * pre);
          float gv = 1.f - 2.f / (ex + 1.f);          // tanh, overflow-safe
          float hn = zreg[e] * hreg[e] + (1.f - zreg[e]) * gv;
          hreg[e] = hn;
          u16 hnb = f2b(hn);
          st_b16_llc(&hb[bvec[e] * 1024 + n_own], hnb);
          seq[(size_t)(bvec[e] * 512 + t) * 1024 + n_own] = hnb;   // plain (L2 ok)
          if (t == 511) hT[bvec[e] * 2048 + n_own] = hn;
        }
      }
      wave_bar(slots, ++ep, ws, lane);
      #pragma unroll
      for (int e = 0; e < 4; ++e) g1[e] = gnext[e];
    }
  }
}

// ---------------- host ----------------
extern "C" void kernel_launch(void* const* d_in, const int* in_sizes, int n_in,
                              void* d_out, int out_size, void* d_ws, size_t ws_size,
                              hipStream_t stream) {
  (void)in_sizes; (void)n_in; (void)out_size; (void)ws_size;
  char* ws = (char*)d_ws;
  const size_t MB = 1024ull * 1024ull;
  u16* gz   = (u16*)(ws + 0);
  u16* gr   = (u16*)(ws + 32 * MB);
  u16* gg   = (u16*)(ws + 64 * MB);
  u16* seq0 = (u16*)(ws + 96 * MB);
  u16* seq1 = (u16*)(ws + 128 * MB);
  u16* xb   = (u16*)(ws + 160 * MB);
  u16* Wh0  = (u16*)(ws + 164 * MB);
  u16* Wh1  = (u16*)(ws + 170 * MB);
  u16* Wx0  = (u16*)(ws + 176 * MB);
  u16* Wx1  = (u16*)(ws + 177 * MB);
  u16* Wyb  = (u16*)(ws + 183 * MB);
  u16* hb   = (u16*)(ws + 184 * MB + 128 * 1024);
  u16* rhb  = (u16*)(ws + 184 * MB + 192 * 1024);
  unsigned* sync0 = (unsigned*)(ws + 184 * MB + 256 * 1024);   // 256 wave-slots
  unsigned* sync1 = sync0 + 256;                               // 256 wave-slots

  hipMemsetAsync(sync0, 0, 2048, stream);

  auto cast = [&](const void* in, u16* out, int n) {
    cast_f32_bf16<<<(n + 255) / 256, 256, 0, stream>>>((const float*)in, out, n);
  };
  cast(d_in[0], xb, 2097152);                               // x
  cast(d_in[3],  Wh0 + 0,       1048576);                   // Whz0
  cast(d_in[6],  Wh0 + 1048576, 1048576);                   // Whr0
  cast(d_in[9],  Wh0 + 2097152, 1048576);                   // Whg0
  cast(d_in[12], Wh1 + 0,       1048576);                   // Whz1
  cast(d_in[15], Wh1 + 1048576, 1048576);                   // Whr1
  cast(d_in[18], Wh1 + 2097152, 1048576);                   // Whg1
  cast(d_in[2],  Wx0 + 0,      131072);                     // Wxz0
  cast(d_in[5],  Wx0 + 131072, 131072);                     // Wxr0
  cast(d_in[8],  Wx0 + 262144, 131072);                     // Wxg0
  cast(d_in[11], Wx1 + 0,       1048576);                   // Wxz1
  cast(d_in[14], Wx1 + 1048576, 1048576);                   // Wxr1
  cast(d_in[17], Wx1 + 2097152, 1048576);                   // Wxg1
  cast(d_in[20], Wyb, 131072);                              // Wy

  dim3 blk(256);
  dim3 gP(128, 8);
  // layer-0 input projections (M=16384, N=1024, K=128) -> gates [t][b][n] bf16
  gemm_bt<<<gP, blk, 0, stream>>>(xb, Wx0 + 0,      16384, 1024, 128, nullptr, nullptr, gz, 1);
  gemm_bt<<<gP, blk, 0, stream>>>(xb, Wx0 + 131072, 16384, 1024, 128, nullptr, nullptr, gr, 1);
  gemm_bt<<<gP, blk, 0, stream>>>(xb, Wx0 + 262144, 16384, 1024, 128, nullptr, nullptr, gg, 1);

  float* y_out = (float*)d_out;
  float* hid = y_out + 2097152;                             // hidden (32,2,1024)

  gru_layer<<<128, dim3(128), 0, stream>>>(Wh0,
      (const float*)d_in[4], (const float*)d_in[7], (const float*)d_in[10],
      gz, gr, gg, (const float*)d_in[1] + 0,
      hb, rhb, seq0, hid + 0, sync0);

  // layer-1 input projections (K=1024)
  gemm_bt<<<gP, blk, 0, stream>>>(seq0, Wx1 + 0,       16384, 1024, 1024, nullptr, nullptr, gz, 1);
  gemm_bt<<<gP, blk, 0, stream>>>(seq0, Wx1 + 1048576, 16384, 1024, 1024, nullptr, nullptr, gr, 1);
  gemm_bt<<<gP, blk, 0, stream>>>(seq0, Wx1 + 2097152, 16384, 1024, 1024, nullptr, nullptr, gg, 1);

  gru_layer<<<128, dim3(128), 0, stream>>>(Wh1,
      (const float*)d_in[13], (const float*)d_in[16], (const float*)d_in[19],
      gz, gr, gg, (const float*)d_in[1] + 1024,
      hb, rhb, seq1, hid + 1024, sync1);

  // output projection y = seq1 @ Wy^T + by  (M=16384, N=128, K=1024), fp32 out
  dim3 gY(128, 1);
  gemm_bt<<<gY, blk, 0, stream>>>(seq1, Wyb, 16384, 128, 1024, (const float*)d_in[21], y_out, nullptr, 0);
}

// Round 6
// 11464.039 us; speedup vs baseline: 1.5820x; 1.5820x over previous
//
#include <hip/hip_runtime.h>

typedef unsigned short u16;
typedef unsigned int u32;
typedef unsigned long long u64;
typedef __bf16 bf16x8 __attribute__((ext_vector_type(8)));
typedef float f32x4 __attribute__((ext_vector_type(4)));

__device__ __forceinline__ u16 f2b(float f) {
  unsigned u = __float_as_uint(f);
  return (u16)((u + 0x7fffu + ((u >> 16) & 1u)) >> 16);
}
__device__ __forceinline__ float b2f(u16 h) {
  return __uint_as_float(((unsigned)h) << 16);
}

// LLC-coherent (agent-scope relaxed => sc-bit accesses, no cache-maint fences)
__device__ __forceinline__ void st_b16_llc(u16* p, u16 v) {
  __hip_atomic_store(p, v, __ATOMIC_RELAXED, __HIP_MEMORY_SCOPE_AGENT);
}
__device__ __forceinline__ bf16x8 ld_frag_llc(const u16* p) {
  union { u64 q[2]; bf16x8 v; } u;
  u.q[0] = __hip_atomic_load((const u64*)p,     __ATOMIC_RELAXED, __HIP_MEMORY_SCOPE_AGENT);
  u.q[1] = __hip_atomic_load((const u64*)p + 1, __ATOMIC_RELAXED, __HIP_MEMORY_SCOPE_AGENT);
  return u.v;
}

// ---------------- generic fp32 -> bf16 cast ----------------
__global__ void cast_f32_bf16(const float* __restrict__ in, u16* __restrict__ out, int n) {
  int i = blockIdx.x * 256 + threadIdx.x;
  if (i < n) out[i] = f2b(in[i]);
}

// ---------------- fence-free device barrier over 256 wgs ----------------
// __syncthreads drains both waves' vmcnt (publishes at LLC). tid0 stores the
// wg's slot (relaxed agent). Wave 0 polls all 256 slots (2 u64 per lane),
// then syncthreads releases wave 1.
__device__ __forceinline__ void wg_bar(unsigned* __restrict__ slots, unsigned ep,
                                       int bid, int tid, int lane, int w) {
  __syncthreads();
  if (tid == 0)
    __hip_atomic_store(&slots[bid], ep, __ATOMIC_RELAXED, __HIP_MEMORY_SCOPE_AGENT);
  if (w == 0) {
    const u64* p64 = (const u64*)slots;
    for (;;) {
      u64 q0 = __hip_atomic_load(&p64[2 * lane],     __ATOMIC_RELAXED, __HIP_MEMORY_SCOPE_AGENT);
      u64 q1 = __hip_atomic_load(&p64[2 * lane + 1], __ATOMIC_RELAXED, __HIP_MEMORY_SCOPE_AGENT);
      u32 m = min(min((u32)q0, (u32)(q0 >> 32)), min((u32)q1, (u32)(q1 >> 32)));
      if (m >= ep) break;
      __builtin_amdgcn_s_sleep(1);
    }
  }
  __syncthreads();
}

// ---------------- tiled bf16 GEMM: C[M,N] = A[M,K] @ B[N,K]^T (fp32 out) ----------------
__global__ __launch_bounds__(256) void gemm_bt(
    const u16* __restrict__ A, const u16* __restrict__ B,
    int M, int N, int K,
    const float* __restrict__ bias, float* __restrict__ Cf)
{
  __shared__ u16 a_sm[128 * 32];
  __shared__ u16 b_sm[128 * 32];
  const int tid = threadIdx.x;
  const int lane = tid & 63;
  const int wid = tid >> 6;
  const int wm = wid >> 1, wn = wid & 1;
  const int m0 = blockIdx.x * 128, n0 = blockIdx.y * 128;
  const int q = lane >> 4, l15 = lane & 15, l3 = lane & 3;

  f32x4 acc[4][4];
  #pragma unroll
  for (int i = 0; i < 4; ++i)
    #pragma unroll
    for (int j = 0; j < 4; ++j) acc[i][j] = (f32x4){0.f, 0.f, 0.f, 0.f};

  for (int kk = 0; kk < K; kk += 32) {
    __syncthreads();
    #pragma unroll
    for (int p = 0; p < 2; ++p) {
      int idx = p * 256 + tid;
      int r = idx >> 2, cch = idx & 3;
      *(uint4*)&a_sm[r * 32 + ((cch ^ (r & 3)) * 8)] =
          *(const uint4*)&A[(size_t)(m0 + r) * K + kk + cch * 8];
      *(uint4*)&b_sm[r * 32 + ((cch ^ (r & 3)) * 8)] =
          *(const uint4*)&B[(size_t)(n0 + r) * K + kk + cch * 8];
    }
    __syncthreads();
    bf16x8 af[4], bfr[4];
    #pragma unroll
    for (int s = 0; s < 4; ++s) {
      int ra = wm * 64 + s * 16 + l15;
      af[s] = *(const bf16x8*)&a_sm[ra * 32 + ((q ^ l3) * 8)];
      int rb = wn * 64 + s * 16 + l15;
      bfr[s] = *(const bf16x8*)&b_sm[rb * 32 + ((q ^ l3) * 8)];
    }
    #pragma unroll
    for (int si = 0; si < 4; ++si)
      #pragma unroll
      for (int sj = 0; sj < 4; ++sj)
        acc[si][sj] = __builtin_amdgcn_mfma_f32_16x16x32_bf16(af[si], bfr[sj], acc[si][sj], 0, 0, 0);
  }

  #pragma unroll
  for (int si = 0; si < 4; ++si)
    #pragma unroll
    for (int sj = 0; sj < 4; ++sj)
      #pragma unroll
      for (int e = 0; e < 4; ++e) {
        int m = m0 + wm * 64 + si * 16 + q * 4 + e;
        int n = n0 + wn * 64 + sj * 16 + l15;
        Cf[(size_t)m * N + n] = acc[si][sj][e] + (bias ? bias[n] : 0.f);
      }
}

// ---------------- fused 2-layer pipelined GRU: 1026 device barriers total ----------------
// 256 wgs x 128 thr. wgs 0-127: layer 0 (n-slice 8 each, K=1024+128 concat [Wh0|Wx0]).
// wgs 128-255: layer 1, one step behind (K=1024+1024 concat [Wh1|Wx1], x-input = h0_t).
// Interval p (t=p>>1, ph=p&1):
//  ph0: L0 phase1(t) reads h0buf[(t-1)&1]; L1 phase1(t-1) reads hb1 + h0buf[(t-1)&1]
//  ph1: L0 phase2(t) -> h0buf[t&1]; L1 phase2(t-1) -> hb1, seq1
// L1 caches the 32 h0 fragments in registers across both phases of a step.
__global__ __launch_bounds__(128, 1) void gru_pipe(
    const u16* __restrict__ Wh0, const u16* __restrict__ Wx0,
    const u16* __restrict__ Wh1, const u16* __restrict__ Wx1,
    const float* __restrict__ bz0, const float* __restrict__ br0, const float* __restrict__ bg0,
    const float* __restrict__ bz1, const float* __restrict__ br1, const float* __restrict__ bg1,
    const u16* __restrict__ xb,                      // [32][512][128] bf16
    const float* __restrict__ h0p,                   // (32,2,1024) fp32
    u16* __restrict__ h0buf,                         // 2 x [32][1024] bf16 rotating
    u16* __restrict__ hb1,                           // [32][1024]
    u16* __restrict__ rh0b, u16* __restrict__ rh1b,  // [32][1024]
    u16* __restrict__ seq1,                          // [32][512][1024] bf16
    float* __restrict__ hid,                         // (32,2,1024) fp32 out
    unsigned* __restrict__ slots)                    // 256 wg slots
{
  __shared__ u16 zr_frag[64 * 512];                  // 64 KB max (L1)
  __shared__ u16 g_frag[64 * 256];                   // 32 KB max

  const int tid = threadIdx.x;
  const int lane = tid & 63;
  const int w = tid >> 6;
  const int bid = blockIdx.x;
  const bool Lyr1 = bid >= 128;
  const int nb = (bid & 127) * 8;
  const int q = lane >> 4, c15 = lane & 15, nl = c15 & 7;
  const int n_own = nb + nl;
  const bool isz = c15 < 8;
  const int brow = w * 16 + c15;                     // A-fragment batch row
  const int KS = Lyr1 ? 64 : 36;                     // K-steps of 32
  const int IN = Lyr1 ? 1024 : 128;
  const u16* Wh = Lyr1 ? Wh1 : Wh0;
  const u16* Wx = Lyr1 ? Wx1 : Wx0;
  const size_t WXG = (size_t)1024 * IN;              // Wx per-gate elems

  // ---- stage concat [Wh | Wx] weights into LDS in MFMA B-frag order ----
  for (int cidx = tid; cidx < KS * 64; cidx += 128) {
    int ks = cidx >> 6, l = cidx & 63;
    int lq = l >> 4, lc = l & 15;
    int row = nb + (lc & 7), gate = (lc < 8) ? 0 : 1;  // z | r
    int k0 = ks * 32 + lq * 8;
    const u16* src = (k0 < 1024)
        ? Wh + (size_t)gate * 1048576 + (size_t)row * 1024 + k0
        : Wx + (size_t)gate * WXG + (size_t)row * IN + (k0 - 1024);
    *(uint4*)&zr_frag[cidx * 8] = *(const uint4*)src;
  }
  for (int gidx = tid; gidx < KS * 32; gidx += 128) {
    int ks = gidx >> 5, s = gidx & 31;
    int lq = s >> 3, r8 = s & 7;
    int row = nb + r8, k0 = ks * 32 + lq * 8;
    const u16* src = (k0 < 1024)
        ? Wh + (size_t)2 * 1048576 + (size_t)row * 1024 + k0
        : Wx + (size_t)2 * WXG + (size_t)row * IN + (k0 - 1024);
    *(uint4*)&g_frag[gidx * 8] = *(const uint4*)src;
  }

  // ---- biases ----
  const float bias1 = isz ? (Lyr1 ? bz1 : bz0)[n_own] : (Lyr1 ? br1 : br0)[n_own];
  const float bias2 = (Lyr1 ? bg1 : bg0)[n_own];

  // ---- init state: z-lanes hold h fp32; publish bf16 ----
  float hreg[4], zreg[4] = {0.f, 0.f, 0.f, 0.f};
  #pragma unroll
  for (int e = 0; e < 4; ++e) {
    int b = w * 16 + q * 4 + e;
    float v = h0p[b * 2048 + (Lyr1 ? 1024 : 0) + n_own];
    hreg[e] = v;
    if (isz)
      st_b16_llc((Lyr1 ? hb1 : h0buf + 32768) + b * 1024 + n_own, f2b(v));
  }
  wg_bar(slots, 1, bid, tid, lane, w);

  bf16x8 xf[4];                                      // L0: x frags for step t
  bf16x8 h0f[32];                                    // L1: h0_t frags (regs across phases)

  for (int p = 0; p < 1026; ++p) {
    const int t = p >> 1, ph = p & 1;
    if (!Lyr1) {
      if (t < 512) {
        if (ph == 0) {
          const u16* hp = h0buf + ((t - 1) & 1) * 32768;
          #pragma unroll
          for (int j = 0; j < 4; ++j)
            xf[j] = *(const bf16x8*)&xb[((size_t)brow * 512 + t) * 128 + j * 32 + q * 8];
          f32x4 a0 = {0.f,0.f,0.f,0.f}, a1 = {0.f,0.f,0.f,0.f};
          #pragma unroll
          for (int ks = 0; ks < 32; ++ks) {
            bf16x8 af = ld_frag_llc(hp + (size_t)brow * 1024 + ks * 32 + q * 8);
            a0 = __builtin_amdgcn_mfma_f32_16x16x32_bf16(af, *(const bf16x8*)&zr_frag[ks * 512 + lane * 8], a0, 0, 0, 0);
          }
          #pragma unroll
          for (int ks = 32; ks < 36; ++ks)
            a1 = __builtin_amdgcn_mfma_f32_16x16x32_bf16(xf[ks - 32], *(const bf16x8*)&zr_frag[ks * 512 + lane * 8], a1, 0, 0, 0);
          float hsh[4];
          #pragma unroll
          for (int e = 0; e < 4; ++e) hsh[e] = __shfl_xor(hreg[e], 8);
          #pragma unroll
          for (int e = 0; e < 4; ++e) {
            float pre = a0[e] + a1[e] + bias1;
            float s = 1.f / (1.f + __expf(-pre));
            if (isz) zreg[e] = s;
            else st_b16_llc(&rh0b[(w * 16 + q * 4 + e) * 1024 + n_own], f2b(s * hsh[e]));
          }
        } else {
          f32x4 a0 = {0.f,0.f,0.f,0.f}, a1 = {0.f,0.f,0.f,0.f};
          #pragma unroll
          for (int ks = 0; ks < 32; ++ks) {
            bf16x8 af = ld_frag_llc(rh0b + (size_t)brow * 1024 + ks * 32 + q * 8);
            a0 = __builtin_amdgcn_mfma_f32_16x16x32_bf16(af, *(const bf16x8*)&g_frag[ks * 256 + (q * 8 + nl) * 8], a0, 0, 0, 0);
          }
          #pragma unroll
          for (int ks = 32; ks < 36; ++ks)
            a1 = __builtin_amdgcn_mfma_f32_16x16x32_bf16(xf[ks - 32], *(const bf16x8*)&g_frag[ks * 256 + (q * 8 + nl) * 8], a1, 0, 0, 0);
          if (isz) {
            u16* hout = h0buf + (t & 1) * 32768;
            #pragma unroll
            for (int e = 0; e < 4; ++e) {
              int b = w * 16 + q * 4 + e;
              float pre = a0[e] + a1[e] + bias2;
              float ex = __expf(2.f * pre);
              float gv = 1.f - 2.f / (ex + 1.f);      // tanh, overflow-safe
              float hn = zreg[e] * hreg[e] + (1.f - zreg[e]) * gv;
              hreg[e] = hn;
              st_b16_llc(&hout[b * 1024 + n_own], f2b(hn));
              if (t == 511) hid[b * 2048 + n_own] = hn;
            }
          }
        }
      }
    } else {
      if (t >= 1) {
        const int s = t - 1;
        if (ph == 0) {
          const u16* hp = h0buf + (s & 1) * 32768;
          #pragma unroll
          for (int j = 0; j < 32; ++j)
            h0f[j] = ld_frag_llc(hp + (size_t)brow * 1024 + j * 32 + q * 8);
          f32x4 a0 = {0.f,0.f,0.f,0.f}, a1 = {0.f,0.f,0.f,0.f};
          #pragma unroll
          for (int ks = 0; ks < 32; ++ks) {
            bf16x8 af = ld_frag_llc(hb1 + (size_t)brow * 1024 + ks * 32 + q * 8);
            a0 = __builtin_amdgcn_mfma_f32_16x16x32_bf16(af, *(const bf16x8*)&zr_frag[ks * 512 + lane * 8], a0, 0, 0, 0);
          }
          #pragma unroll
          for (int ks = 32; ks < 64; ++ks)
            a1 = __builtin_amdgcn_mfma_f32_16x16x32_bf16(h0f[ks - 32], *(const bf16x8*)&zr_frag[ks * 512 + lane * 8], a1, 0, 0, 0);
          float hsh[4];
          #pragma unroll
          for (int e = 0; e < 4; ++e) hsh[e] = __shfl_xor(hreg[e], 8);
          #pragma unroll
          for (int e = 0; e < 4; ++e) {
            float pre = a0[e] + a1[e] + bias1;
            float sg = 1.f / (1.f + __expf(-pre));
            if (isz) zreg[e] = sg;
            else st_b16_llc(&rh1b[(w * 16 + q * 4 + e) * 1024 + n_own], f2b(sg * hsh[e]));
          }
        } else {
          f32x4 a0 = {0.f,0.f,0.f,0.f}, a1 = {0.f,0.f,0.f,0.f};
          #pragma unroll
          for (int ks = 0; ks < 32; ++ks) {
            bf16x8 af = ld_frag_llc(rh1b + (size_t)brow * 1024 + ks * 32 + q * 8);
            a0 = __builtin_amdgcn_mfma_f32_16x16x32_bf16(af, *(const bf16x8*)&g_frag[ks * 256 + (q * 8 + nl) * 8], a0, 0, 0, 0);
          }
          #pragma unroll
          for (int ks = 32; ks < 64; ++ks)
            a1 = __builtin_amdgcn_mfma_f32_16x16x32_bf16(h0f[ks - 32], *(const bf16x8*)&g_frag[ks * 256 + (q * 8 + nl) * 8], a1, 0, 0, 0);
          if (isz) {
            #pragma unroll
            for (int e = 0; e < 4; ++e) {
              int b = w * 16 + q * 4 + e;
              float pre = a0[e] + a1[e] + bias2;
              float ex = __expf(2.f * pre);
              float gv = 1.f - 2.f / (ex + 1.f);
              float hn = zreg[e] * hreg[e] + (1.f - zreg[e]) * gv;
              hreg[e] = hn;
              u16 hnb = f2b(hn);
              st_b16_llc(&hb1[b * 1024 + n_own], hnb);
              seq1[((size_t)b * 512 + s) * 1024 + n_own] = hnb;   // plain store
              if (s == 511) hid[1024 + b * 2048 + n_own] = hn;
            }
          }
        }
      }
    }
    wg_bar(slots, p + 2, bid, tid, lane, w);
  }
}

// ---------------- host ----------------
extern "C" void kernel_launch(void* const* d_in, const int* in_sizes, int n_in,
                              void* d_out, int out_size, void* d_ws, size_t ws_size,
                              hipStream_t stream) {
  (void)in_sizes; (void)n_in; (void)out_size; (void)ws_size;
  char* ws = (char*)d_ws;
  const size_t MB = 1024ull * 1024ull;
  u16* seq1 = (u16*)(ws + 0);                         // 32 MB
  u16* xb   = (u16*)(ws + 32 * MB);                   // 4 MB
  u16* Wh0  = (u16*)(ws + 36 * MB);                   // 6 MB
  u16* Wh1  = (u16*)(ws + 42 * MB);                   // 6 MB
  u16* Wx0  = (u16*)(ws + 48 * MB);                   // 0.75 MB
  u16* Wx1  = (u16*)(ws + 49 * MB);                   // 6 MB
  u16* Wyb  = (u16*)(ws + 55 * MB);                   // 0.25 MB
  u16* h0buf = (u16*)(ws + 56 * MB);                  // 2 x 64 KB
  u16* hb1  = (u16*)(ws + 56 * MB + 128 * 1024);      // 64 KB
  u16* rh0b = (u16*)(ws + 56 * MB + 192 * 1024);      // 64 KB
  u16* rh1b = (u16*)(ws + 56 * MB + 256 * 1024);      // 64 KB
  unsigned* slots = (unsigned*)(ws + 56 * MB + 320 * 1024);  // 1 KB

  hipMemsetAsync(slots, 0, 1024, stream);

  auto cast = [&](const void* in, u16* out, int n) {
    cast_f32_bf16<<<(n + 255) / 256, 256, 0, stream>>>((const float*)in, out, n);
  };
  cast(d_in[0], xb, 2097152);                               // x
  cast(d_in[3],  Wh0 + 0,       1048576);                   // Whz0
  cast(d_in[6],  Wh0 + 1048576, 1048576);                   // Whr0
  cast(d_in[9],  Wh0 + 2097152, 1048576);                   // Whg0
  cast(d_in[12], Wh1 + 0,       1048576);                   // Whz1
  cast(d_in[15], Wh1 + 1048576, 1048576);                   // Whr1
  cast(d_in[18], Wh1 + 2097152, 1048576);                   // Whg1
  cast(d_in[2],  Wx0 + 0,      131072);                     // Wxz0
  cast(d_in[5],  Wx0 + 131072, 131072);                     // Wxr0
  cast(d_in[8],  Wx0 + 262144, 131072);                     // Wxg0
  cast(d_in[11], Wx1 + 0,       1048576);                   // Wxz1
  cast(d_in[14], Wx1 + 1048576, 1048576);                   // Wxr1
  cast(d_in[17], Wx1 + 2097152, 1048576);                   // Wxg1
  cast(d_in[20], Wyb, 131072);                              // Wy

  float* y_out = (float*)d_out;
  float* hid = y_out + 2097152;                             // hidden (32,2,1024)

  gru_pipe<<<256, dim3(128), 0, stream>>>(
      Wh0, Wx0, Wh1, Wx1,
      (const float*)d_in[4],  (const float*)d_in[7],  (const float*)d_in[10],
      (const float*)d_in[13], (const float*)d_in[16], (const float*)d_in[19],
      xb, (const float*)d_in[1],
      h0buf, hb1, rh0b, rh1b, seq1, hid, slots);

  // output projection y = seq1 @ Wy^T + by  (M=16384, N=128, K=1024)
  gemm_bt<<<dim3(128, 1), dim3(256), 0, stream>>>(
      seq1, Wyb, 16384, 128, 1024, (const float*)d_in[21], y_out);
}